// Round 1
// baseline (169.412 us; speedup 1.0000x reference)
//
#include <hip/hip_runtime.h>
#include <hip/hip_bf16.h>
#include <stdint.h>

typedef __attribute__((ext_vector_type(4))) float f32x4;
typedef __attribute__((ext_vector_type(8))) short short8;

#define NN 4096      // nodes
#define FIN 128
#define FHID 64
#define BATCH 32
#define NJ 2048      // BATCH * FHID

// ---------- helpers ----------
__device__ __forceinline__ unsigned short f2bf(float f) {
  unsigned u = __builtin_bit_cast(unsigned, f);
  u = (u + 0x7FFFu + ((u >> 16) & 1u)) >> 16;   // RNE
  return (unsigned short)u;
}
__device__ __forceinline__ float bf2f(unsigned short h) {
  unsigned u = ((unsigned)h) << 16;
  return __builtin_bit_cast(float, u);
}
__device__ __forceinline__ void gload_lds16(const void* g, void* l) {
  __builtin_amdgcn_global_load_lds(
      (const __attribute__((address_space(1))) unsigned int*)g,
      (__attribute__((address_space(3))) unsigned int*)l, 16, 0, 0);
}

// ---------- K0: adj fp32 -> bf16 ----------
__global__ __launch_bounds__(256) void k_convert(const float* __restrict__ adj,
                                                 unsigned short* __restrict__ adjb) {
  long i = (long)blockIdx.x * 256 + threadIdx.x;   // one float4 per thread
  const f32x4* in = (const f32x4*)adj;
  f32x4 v = in[i];
  ushort4 o;
  o.x = f2bf(v.x); o.y = f2bf(v.y); o.z = f2bf(v.z); o.w = f2bf(v.w);
  *(ushort4*)(adjb + i * 4) = o;
}

// ---------- K1: St[b*64+h][m] = sum_f x[b][m][f] * W1[f][h]  (bf16 out) ----------
__global__ __launch_bounds__(256) void k_support(const float* __restrict__ x,
                                                 const float* __restrict__ W1,
                                                 unsigned short* __restrict__ St) {
  __shared__ float W1s[FIN * FHID];   // 32 KB
  int tid = threadIdx.x;
  for (int i = tid; i < FIN * FHID; i += 256) W1s[i] = W1[i];
  __syncthreads();

  long r = (long)blockIdx.x * 256 + tid;     // row id: b*4096 + m
  int b = (int)(r >> 12);
  int m = (int)(r & 4095);
  const f32x4* xr = (const f32x4*)(x + r * FIN);

  f32x4 acc[16];
  f32x4 z = {0.f, 0.f, 0.f, 0.f};
  #pragma unroll
  for (int i = 0; i < 16; ++i) acc[i] = z;

  #pragma unroll 8
  for (int f4 = 0; f4 < FIN / 4; ++f4) {
    f32x4 xv = xr[f4];
    const f32x4* wrow = (const f32x4*)(W1s + (f4 * 4) * FHID);
    #pragma unroll
    for (int k = 0; k < 4; ++k) {
      float xf = xv[k];
      #pragma unroll
      for (int hq = 0; hq < 16; ++hq) acc[hq] += xf * wrow[k * 16 + hq];
    }
  }
  unsigned short* dst = St + (long)(b * FHID) * NN + m;
  #pragma unroll
  for (int hq = 0; hq < 16; ++hq)
    #pragma unroll
    for (int k = 0; k < 4; ++k)
      dst[(long)(hq * 4 + k) * NN] = f2bf(acc[hq][k]);
}

// ---------- K2: H = relu(adjb @ St^T + b1)   (m97-structure MFMA GEMM) ----------
// A = adjb [4096][4096] bf16 row-major (K along rows)
// Bt = St  [2048][4096] bf16 row-major (B^T layout, K along rows)
// H  = [4096][2048] bf16
__global__ __launch_bounds__(256, 2) void k_gemm(const unsigned short* __restrict__ A,
                                                 const unsigned short* __restrict__ Bt,
                                                 const float* __restrict__ b1,
                                                 unsigned short* __restrict__ H) {
  __shared__ unsigned short As[128 * 32];  // 8 KB
  __shared__ unsigned short Bs[128 * 32];  // 8 KB

  const int tid  = threadIdx.x;
  const int lane = tid & 63;
  const int wave = tid >> 6;          // 4 waves, 2x2 wave grid
  const int wr = wave >> 1, wc = wave & 1;
  const int bm = blockIdx.x * 128;    // n (node) dim
  const int bn = blockIdx.y * 128;    // j = b*64+h dim

  f32x4 z = {0.f, 0.f, 0.f, 0.f};
  f32x4 acc[4][4];
  #pragma unroll
  for (int i = 0; i < 4; ++i)
    #pragma unroll
    for (int j = 0; j < 4; ++j) acc[i][j] = z;

  // staging geometry: tile 128 rows x 32 cols bf16 = 8192 B = 8 chunks of 1024 B
  // chunk c: LDS bytes [c*1024, +1024), lane l covers 16 B at c*1024 + l*16
  const int off0 = wave * 1024 + lane * 16;          // chunk = wave
  const int off1 = (wave + 4) * 1024 + lane * 16;    // chunk = wave+4
  const int row0 = off0 >> 6, col0 = (off0 & 63) >> 1;   // 64 B per row (32 bf16)
  const int row1 = off1 >> 6, col1 = (off1 & 63) >> 1;

  const unsigned short* gA0 = A  + (long)(bm + row0) * NN + col0;
  const unsigned short* gA1 = A  + (long)(bm + row1) * NN + col1;
  const unsigned short* gB0 = Bt + (long)(bn + row0) * NN + col0;
  const unsigned short* gB1 = Bt + (long)(bn + row1) * NN + col1;
  unsigned short* lA0 = As + wave * 512;        // 1024 B = 512 ushorts
  unsigned short* lA1 = As + (wave + 4) * 512;
  unsigned short* lB0 = Bs + wave * 512;
  unsigned short* lB1 = Bs + (wave + 4) * 512;

  const int fr = lane & 15;          // fragment row
  const int fk = (lane >> 4) * 8;    // fragment k offset

  for (int k0 = 0; k0 < NN; k0 += 32) {
    gload_lds16(gA0 + k0, lA0);
    gload_lds16(gA1 + k0, lA1);
    gload_lds16(gB0 + k0, lB0);
    gload_lds16(gB1 + k0, lB1);
    __syncthreads();

    short8 a[4], b[4];
    #pragma unroll
    for (int mi = 0; mi < 4; ++mi)
      a[mi] = *(const short8*)&As[(wr * 64 + mi * 16 + fr) * 32 + fk];
    #pragma unroll
    for (int ni = 0; ni < 4; ++ni)
      b[ni] = *(const short8*)&Bs[(wc * 64 + ni * 16 + fr) * 32 + fk];

    #pragma unroll
    for (int mi = 0; mi < 4; ++mi)
      #pragma unroll
      for (int ni = 0; ni < 4; ++ni)
        acc[mi][ni] = __builtin_amdgcn_mfma_f32_16x16x32_bf16(a[mi], b[ni], acc[mi][ni], 0, 0, 0);
    __syncthreads();
  }

  // epilogue: bias + relu, store bf16
  const int cr = (lane >> 4) * 4;
  const int cc = lane & 15;
  #pragma unroll
  for (int ni = 0; ni < 4; ++ni) {
    int col = bn + wc * 64 + ni * 16 + cc;     // j
    float bias = b1[col & 63];
    #pragma unroll
    for (int mi = 0; mi < 4; ++mi) {
      #pragma unroll
      for (int r = 0; r < 4; ++r) {
        int row = bm + wr * 64 + mi * 16 + cr + r;   // n
        float v = acc[mi][ni][r] + bias;
        v = v > 0.f ? v : 0.f;
        H[(long)row * NJ + col] = f2bf(v);
      }
    }
  }
}

// ---------- K3: partial[b][c][h] = sum_{n in chunk c} adj[q_b][n] * H[n][b*64+h] ----------
__global__ __launch_bounds__(256) void k_agg(const float* __restrict__ adj,
                                             const int* __restrict__ q_ids,
                                             const unsigned short* __restrict__ H,
                                             float* __restrict__ partial) {
  int b = blockIdx.x;        // 0..31
  int c = blockIdx.y;        // 0..15
  int h = threadIdx.x & 63;
  int w = threadIdx.x >> 6;
  int q = q_ids[b];
  const float* arow = adj + (long)q * NN;
  int j = b * FHID + h;
  float s = 0.f;
  int n0 = c * 256;
  for (int n = n0 + w; n < n0 + 256; n += 4)
    s += arow[n] * bf2f(H[(long)n * NJ + j]);
  __shared__ float red[4][64];
  red[w][h] = s;
  __syncthreads();
  if (w == 0)
    partial[((b << 4) + c) * 64 + h] = red[0][h] + red[1][h] + red[2][h] + red[3][h];
}

// ---------- K4: out[b][l] = sum_h agg[b][h]*W2[h][l] + b2[l] ----------
__global__ __launch_bounds__(1024) void k_out(const float* __restrict__ partial,
                                              const float* __restrict__ W2,
                                              const float* __restrict__ b2,
                                              float* __restrict__ out) {
  __shared__ float aggs[BATCH * FHID];   // 2048
  int t = threadIdx.x;
  for (int idx = t; idx < BATCH * FHID; idx += 1024) {
    int base = (idx >> 6) * (16 * 64) + (idx & 63);
    float s = 0.f;
    #pragma unroll
    for (int c = 0; c < 16; ++c) s += partial[base + c * 64];
    aggs[idx] = s;
  }
  __syncthreads();
  int b = t >> 5, l = t & 31;
  float o = b2[l];
  #pragma unroll
  for (int h = 0; h < FHID; ++h) o += aggs[b * FHID + h] * W2[h * 32 + l];
  out[b * 32 + l] = o;
}

extern "C" void kernel_launch(void* const* d_in, const int* in_sizes, int n_in,
                              void* d_out, int out_size, void* d_ws, size_t ws_size,
                              hipStream_t stream) {
  const float* x   = (const float*)d_in[0];
  const int*   q   = (const int*)d_in[1];
  const float* adj = (const float*)d_in[2];
  const float* W1  = (const float*)d_in[3];
  const float* b1  = (const float*)d_in[4];
  const float* W2  = (const float*)d_in[5];
  const float* b2  = (const float*)d_in[6];
  float* out = (float*)d_out;

  char* ws = (char*)d_ws;
  unsigned short* adjb   = (unsigned short*)ws;                              // 32 MB
  unsigned short* St     = (unsigned short*)(ws + (size_t)32 * 1024 * 1024); // 16 MB
  unsigned short* H      = (unsigned short*)(ws + (size_t)48 * 1024 * 1024); // 16 MB
  float*          partial= (float*)(ws + (size_t)64 * 1024 * 1024);          // 128 KB

  // K0: adj -> bf16  (16.78M elems / 4 per thread)
  k_convert<<<(NN * NN / 4) / 256, 256, 0, stream>>>(adj, adjb);
  // K1: support^T
  k_support<<<(BATCH * NN) / 256, 256, 0, stream>>>(x, W1, St);
  // K2: big GEMM + bias + relu
  dim3 g2(NN / 128, NJ / 128);
  k_gemm<<<g2, 256, 0, stream>>>(adjb, St, b1, H);
  // K3: row-gather aggregation
  dim3 g3(BATCH, 16);
  k_agg<<<g3, 256, 0, stream>>>(adj, q, H, partial);
  // K4: final tiny GEMM
  k_out<<<1, 1024, 0, stream>>>(partial, W2, b2, out);
}

// Round 2
// 168.795 us; speedup vs baseline: 1.0037x; 1.0037x over previous
//
#include <hip/hip_runtime.h>
#include <hip/hip_bf16.h>
#include <stdint.h>

typedef __attribute__((ext_vector_type(4))) float f32x4;
typedef __attribute__((ext_vector_type(8))) short short8;

#define NN 4096      // nodes
#define FIN 128
#define FHID 64
#define BATCH 32
#define NJ 2048      // BATCH * FHID

// ---------- helpers ----------
__device__ __forceinline__ unsigned short f2bf(float f) {
  unsigned u = __builtin_bit_cast(unsigned, f);
  u = (u + 0x7FFFu + ((u >> 16) & 1u)) >> 16;   // RNE
  return (unsigned short)u;
}
__device__ __forceinline__ float bf2f(unsigned short h) {
  unsigned u = ((unsigned)h) << 16;
  return __builtin_bit_cast(float, u);
}
__device__ __forceinline__ void gload_lds16(const void* g, void* l) {
  __builtin_amdgcn_global_load_lds(
      (const __attribute__((address_space(1))) unsigned int*)g,
      (__attribute__((address_space(3))) unsigned int*)l, 16, 0, 0);
}

// ---------- K0: adj fp32 -> bf16 ----------
__global__ __launch_bounds__(256) void k_convert(const float* __restrict__ adj,
                                                 unsigned short* __restrict__ adjb) {
  long i = (long)blockIdx.x * 256 + threadIdx.x;   // one float4 per thread
  const f32x4* in = (const f32x4*)adj;
  f32x4 v = in[i];
  ushort4 o;
  o.x = f2bf(v.x); o.y = f2bf(v.y); o.z = f2bf(v.z); o.w = f2bf(v.w);
  *(ushort4*)(adjb + i * 4) = o;
}

// ---------- K1: St[b*64+h][m] = sum_f x[b][m][f] * W1[f][h]  (bf16 out) ----------
__global__ __launch_bounds__(256) void k_support(const float* __restrict__ x,
                                                 const float* __restrict__ W1,
                                                 unsigned short* __restrict__ St) {
  __shared__ float W1s[FIN * FHID];   // 32 KB
  int tid = threadIdx.x;
  for (int i = tid; i < FIN * FHID; i += 256) W1s[i] = W1[i];
  __syncthreads();

  long r = (long)blockIdx.x * 256 + tid;     // row id: b*4096 + m
  int b = (int)(r >> 12);
  int m = (int)(r & 4095);
  const f32x4* xr = (const f32x4*)(x + r * FIN);

  f32x4 acc[16];
  f32x4 z = {0.f, 0.f, 0.f, 0.f};
  #pragma unroll
  for (int i = 0; i < 16; ++i) acc[i] = z;

  #pragma unroll 8
  for (int f4 = 0; f4 < FIN / 4; ++f4) {
    f32x4 xv = xr[f4];
    const f32x4* wrow = (const f32x4*)(W1s + (f4 * 4) * FHID);
    #pragma unroll
    for (int k = 0; k < 4; ++k) {
      float xf = xv[k];
      #pragma unroll
      for (int hq = 0; hq < 16; ++hq) acc[hq] += xf * wrow[k * 16 + hq];
    }
  }
  unsigned short* dst = St + (long)(b * FHID) * NN + m;
  #pragma unroll
  for (int hq = 0; hq < 16; ++hq)
    #pragma unroll
    for (int k = 0; k < 4; ++k)
      dst[(long)(hq * 4 + k) * NN] = f2bf(acc[hq][k]);
}

// ---------- K2: H = relu(adjb @ St^T + b1) ----------
// BM=256 x BN=128, BK=64, 8 waves (4M x 2N), double-buffered LDS,
// counted vmcnt(6) 2-deep pipeline, XOR-swizzled LDS (byte ^= (row&7)<<4)
// applied via pre-swizzled global source (gload_lds writes linearly).
// A = adjb [4096][4096] bf16 row-major; Bt = St [2048][4096] bf16 (B^T, K-major)
// H = [4096][2048] bf16
__global__ __launch_bounds__(512, 1) void k_gemm(const unsigned short* __restrict__ A,
                                                 const unsigned short* __restrict__ Bt,
                                                 const float* __restrict__ b1,
                                                 unsigned short* __restrict__ H) {
  // A tile: 256x64 bf16 = 32KB (16384 ushorts) x2 dbuf
  // B tile: 128x64 bf16 = 16KB ( 8192 ushorts) x2 dbuf
  __shared__ unsigned short As[2 * 16384];
  __shared__ unsigned short Bs[2 * 8192];

  const int tid  = threadIdx.x;
  const int lane = tid & 63;
  const int wv   = tid >> 6;          // 8 waves: 4M x 2N
  const int wr   = wv >> 1;           // 0..3  (M)
  const int wc   = wv & 1;            // 0..1  (N)
  const int bm   = blockIdx.x * 256;  // node dim
  const int bn   = blockIdx.y * 128;  // j = b*64+h dim

  // fragment addressing
  const int fr = lane & 15;           // fragment row
  const int fq = lane >> 4;           // k quarter (0..3)
  const int xorv = (fr & 7) << 4;     // swizzle term (row&7 == fr&7 for all frags)

  // staging addressing: thread t covers 16B LDS slot t*16 (+ i*8192 per chunk)
  // slot s -> row = s>>7, kb_swz = s&127, kb = kb_swz ^ ((row&7)<<4)
  const int srow = tid >> 3;                              // 0..63 (+64 per chunk)
  const int skb  = ((tid & 7) << 4) ^ ((srow & 7) << 4);  // byte col in [0,128)
  const unsigned short* ga = A  + (size_t)(bm + srow) * NN + (skb >> 1);
  const unsigned short* gb = Bt + (size_t)(bn + srow) * NN + (skb >> 1);

  f32x4 z = {0.f, 0.f, 0.f, 0.f};
  f32x4 acc[4][4];
  #pragma unroll
  for (int i = 0; i < 4; ++i)
    #pragma unroll
    for (int j = 0; j < 4; ++j) acc[i][j] = z;

  // ---- prologue: stage tiles 0 (buf0) and 1 (buf1) ----
  #pragma unroll
  for (int i = 0; i < 4; ++i)
    gload_lds16(ga + (size_t)i * 64 * NN, As + wv * 512 + i * 4096);
  #pragma unroll
  for (int i = 0; i < 2; ++i)
    gload_lds16(gb + (size_t)i * 64 * NN, Bs + wv * 512 + i * 4096);
  #pragma unroll
  for (int i = 0; i < 4; ++i)
    gload_lds16(ga + (size_t)i * 64 * NN + 64, As + 16384 + wv * 512 + i * 4096);
  #pragma unroll
  for (int i = 0; i < 2; ++i)
    gload_lds16(gb + (size_t)i * 64 * NN + 64, Bs + 8192 + wv * 512 + i * 4096);
  asm volatile("s_waitcnt vmcnt(6)" ::: "memory");   // tile0 landed, tile1 in flight
  __builtin_amdgcn_s_barrier();

  // ---- main loop: 64 K-tiles ----
  #pragma unroll 2
  for (int t = 0; t < 64; ++t) {
    const int cur = t & 1;
    const unsigned short* Ab = As + cur * 16384;
    const unsigned short* Bb = Bs + cur * 8192;

    #pragma unroll
    for (int ks = 0; ks < 2; ++ks) {
      const int ko = (((ks << 6) + (fq << 4)) ^ xorv) >> 1;  // ushort offset in row
      short8 av[4], bv[4];
      #pragma unroll
      for (int mi = 0; mi < 4; ++mi)
        av[mi] = *(const short8*)(Ab + (wr * 64 + mi * 16 + fr) * 64 + ko);
      #pragma unroll
      for (int ni = 0; ni < 4; ++ni)
        bv[ni] = *(const short8*)(Bb + (wc * 64 + ni * 16 + fr) * 64 + ko);
      #pragma unroll
      for (int mi = 0; mi < 4; ++mi)
        #pragma unroll
        for (int ni = 0; ni < 4; ++ni)
          acc[mi][ni] = __builtin_amdgcn_mfma_f32_16x16x32_bf16(av[mi], bv[ni], acc[mi][ni], 0, 0, 0);
    }

    if (t < 62) {
      // all lanes' ds_read data in VGPRs before anyone overwrites this buffer
      asm volatile("s_waitcnt lgkmcnt(0)" ::: "memory");
      __builtin_amdgcn_s_barrier();
      const int k2 = (t + 2) << 6;     // element col of tile t+2
      #pragma unroll
      for (int i = 0; i < 4; ++i)
        gload_lds16(ga + (size_t)i * 64 * NN + k2, As + cur * 16384 + wv * 512 + i * 4096);
      #pragma unroll
      for (int i = 0; i < 2; ++i)
        gload_lds16(gb + (size_t)i * 64 * NN + k2, Bs + cur * 8192 + wv * 512 + i * 4096);
      // wait for tile t+1 (6 oldest), keep tile t+2's 6 loads in flight
      asm volatile("s_waitcnt vmcnt(6)" ::: "memory");
      __builtin_amdgcn_s_barrier();
    } else if (t == 62) {
      asm volatile("s_waitcnt lgkmcnt(0)" ::: "memory");
      __builtin_amdgcn_s_barrier();
      asm volatile("s_waitcnt vmcnt(0)" ::: "memory");   // drain: tile 63 ready
      __builtin_amdgcn_s_barrier();
    }
  }

  // ---- epilogue: bias + relu, store bf16 ----
  const int cr = (lane >> 4) * 4;
  const int cc = lane & 15;
  #pragma unroll
  for (int ni = 0; ni < 4; ++ni) {
    int col = bn + wc * 64 + ni * 16 + cc;     // j
    float bias = b1[(ni * 16 + cc) & 63];
    #pragma unroll
    for (int mi = 0; mi < 4; ++mi) {
      #pragma unroll
      for (int r = 0; r < 4; ++r) {
        int row = bm + wr * 64 + mi * 16 + cr + r;   // n
        float v = acc[mi][ni][r] + bias;
        v = v > 0.f ? v : 0.f;
        H[(long)row * NJ + col] = f2bf(v);
      }
    }
  }
}

// ---------- K3: partial[b][c][h] = sum_{n in chunk c} adj[q_b][n] * H[n][b*64+h] ----------
__global__ __launch_bounds__(256) void k_agg(const float* __restrict__ adj,
                                             const int* __restrict__ q_ids,
                                             const unsigned short* __restrict__ H,
                                             float* __restrict__ partial) {
  int b = blockIdx.x;        // 0..31
  int c = blockIdx.y;        // 0..15
  int h = threadIdx.x & 63;
  int w = threadIdx.x >> 6;
  int q = q_ids[b];
  const float* arow = adj + (long)q * NN;
  int j = b * FHID + h;
  float s = 0.f;
  int n0 = c * 256;
  for (int n = n0 + w; n < n0 + 256; n += 4)
    s += arow[n] * bf2f(H[(long)n * NJ + j]);
  __shared__ float red[4][64];
  red[w][h] = s;
  __syncthreads();
  if (w == 0)
    partial[((b << 4) + c) * 64 + h] = red[0][h] + red[1][h] + red[2][h] + red[3][h];
}

// ---------- K4: out[b][l] = sum_h agg[b][h]*W2[h][l] + b2[l] ----------
__global__ __launch_bounds__(1024) void k_out(const float* __restrict__ partial,
                                              const float* __restrict__ W2,
                                              const float* __restrict__ b2,
                                              float* __restrict__ out) {
  __shared__ float aggs[BATCH * FHID];   // 2048
  int t = threadIdx.x;
  for (int idx = t; idx < BATCH * FHID; idx += 1024) {
    int base = (idx >> 6) * (16 * 64) + (idx & 63);
    float s = 0.f;
    #pragma unroll
    for (int c = 0; c < 16; ++c) s += partial[base + c * 64];
    aggs[idx] = s;
  }
  __syncthreads();
  int b = t >> 5, l = t & 31;
  float o = b2[l];
  #pragma unroll
  for (int h = 0; h < FHID; ++h) o += aggs[b * FHID + h] * W2[h * 32 + l];
  out[b * 32 + l] = o;
}

extern "C" void kernel_launch(void* const* d_in, const int* in_sizes, int n_in,
                              void* d_out, int out_size, void* d_ws, size_t ws_size,
                              hipStream_t stream) {
  const float* x   = (const float*)d_in[0];
  const int*   q   = (const int*)d_in[1];
  const float* adj = (const float*)d_in[2];
  const float* W1  = (const float*)d_in[3];
  const float* b1  = (const float*)d_in[4];
  const float* W2  = (const float*)d_in[5];
  const float* b2  = (const float*)d_in[6];
  float* out = (float*)d_out;

  char* ws = (char*)d_ws;
  unsigned short* adjb   = (unsigned short*)ws;                              // 32 MB
  unsigned short* St     = (unsigned short*)(ws + (size_t)32 * 1024 * 1024); // 16 MB
  unsigned short* H      = (unsigned short*)(ws + (size_t)48 * 1024 * 1024); // 16 MB
  float*          partial= (float*)(ws + (size_t)64 * 1024 * 1024);          // 128 KB

  // K0: adj -> bf16  (16.78M elems / 4 per thread)
  k_convert<<<(NN * NN / 4) / 256, 256, 0, stream>>>(adj, adjb);
  // K1: support^T
  k_support<<<(BATCH * NN) / 256, 256, 0, stream>>>(x, W1, St);
  // K2: big GEMM + bias + relu  (256x128 tiles)
  dim3 g2(NN / 256, NJ / 128);
  k_gemm<<<g2, 512, 0, stream>>>(adjb, St, b1, H);
  // K3: row-gather aggregation
  dim3 g3(BATCH, 16);
  k_agg<<<g3, 256, 0, stream>>>(adj, q, H, partial);
  // K4: final tiny GEMM
  k_out<<<1, 1024, 0, stream>>>(partial, W2, b2, out);
}

// Round 3
// 163.205 us; speedup vs baseline: 1.0380x; 1.0343x over previous
//
#include <hip/hip_runtime.h>
#include <hip/hip_bf16.h>
#include <stdint.h>

typedef __attribute__((ext_vector_type(4))) float f32x4;
typedef __attribute__((ext_vector_type(8))) short short8;

#define NN 4096      // nodes
#define FIN 128
#define FHID 64
#define BATCH 32
#define NJ 2048      // BATCH * FHID

// ---------- helpers ----------
__device__ __forceinline__ unsigned short f2bf(float f) {
  unsigned u = __builtin_bit_cast(unsigned, f);
  u = (u + 0x7FFFu + ((u >> 16) & 1u)) >> 16;   // RNE
  return (unsigned short)u;
}
__device__ __forceinline__ float bf2f(unsigned short h) {
  unsigned u = ((unsigned)h) << 16;
  return __builtin_bit_cast(float, u);
}
__device__ __forceinline__ void gload_lds16(const void* g, void* l) {
  __builtin_amdgcn_global_load_lds(
      (const __attribute__((address_space(1))) unsigned int*)g,
      (__attribute__((address_space(3))) unsigned int*)l, 16, 0, 0);
}

// ---------- K0: adj fp32 -> bf16 ----------
__global__ __launch_bounds__(256) void k_convert(const float* __restrict__ adj,
                                                 unsigned short* __restrict__ adjb) {
  long i = (long)blockIdx.x * 256 + threadIdx.x;   // one float4 per thread
  const f32x4* in = (const f32x4*)adj;
  f32x4 v = in[i];
  ushort4 o;
  o.x = f2bf(v.x); o.y = f2bf(v.y); o.z = f2bf(v.z); o.w = f2bf(v.w);
  *(ushort4*)(adjb + i * 4) = o;
}

// ---------- K1: St[b*64+h][m] = sum_f x[b][m][f] * W1[f][h]  (bf16 out) ----------
__global__ __launch_bounds__(256) void k_support(const float* __restrict__ x,
                                                 const float* __restrict__ W1,
                                                 unsigned short* __restrict__ St) {
  __shared__ float W1s[FIN * FHID];   // 32 KB
  int tid = threadIdx.x;
  for (int i = tid; i < FIN * FHID; i += 256) W1s[i] = W1[i];
  __syncthreads();

  long r = (long)blockIdx.x * 256 + tid;     // row id: b*4096 + m
  int b = (int)(r >> 12);
  int m = (int)(r & 4095);
  const f32x4* xr = (const f32x4*)(x + r * FIN);

  f32x4 acc[16];
  f32x4 z = {0.f, 0.f, 0.f, 0.f};
  #pragma unroll
  for (int i = 0; i < 16; ++i) acc[i] = z;

  #pragma unroll 8
  for (int f4 = 0; f4 < FIN / 4; ++f4) {
    f32x4 xv = xr[f4];
    const f32x4* wrow = (const f32x4*)(W1s + (f4 * 4) * FHID);
    #pragma unroll
    for (int k = 0; k < 4; ++k) {
      float xf = xv[k];
      #pragma unroll
      for (int hq = 0; hq < 16; ++hq) acc[hq] += xf * wrow[k * 16 + hq];
    }
  }
  unsigned short* dst = St + (long)(b * FHID) * NN + m;
  #pragma unroll
  for (int hq = 0; hq < 16; ++hq)
    #pragma unroll
    for (int k = 0; k < 4; ++k)
      dst[(long)(hq * 4 + k) * NN] = f2bf(acc[hq][k]);
}

// ---------- K2: H = relu(adjb @ St^T + b1) ----------
// BM=256 x BN=128, BK=64, 8 waves (4M x 2N), TRI-buffered LDS (144 KB),
// prefetch distance 2 with issue-early staging interleaved into compute
// phases, counted vmcnt(6), ONE barrier per K-tile, setprio around MFMA,
// XOR-swizzled LDS (byte ^= (row&7)<<4) via pre-swizzled global source.
__global__ __launch_bounds__(512, 1) void k_gemm(const unsigned short* __restrict__ A,
                                                 const unsigned short* __restrict__ Bt,
                                                 const float* __restrict__ b1,
                                                 unsigned short* __restrict__ H) {
  // per-tile: A 256x64 bf16 = 32KB (16384 us), B 128x64 bf16 = 16KB (8192 us)
  __shared__ unsigned short As[3 * 16384];   // 96 KB
  __shared__ unsigned short Bs[3 * 8192];    // 48 KB

  const int tid  = threadIdx.x;
  const int lane = tid & 63;
  const int wv   = tid >> 6;          // 8 waves: 4M x 2N
  const int wr   = wv >> 1;           // 0..3  (M)
  const int wc   = wv & 1;            // 0..1  (N)
  const int bm   = blockIdx.x * 256;  // node dim
  const int bn   = blockIdx.y * 128;  // j = b*64+h dim

  // fragment addressing
  const int fr = lane & 15;           // fragment row
  const int fq = lane >> 4;           // k quarter (0..3)
  const int xorv = (fr & 7) << 4;     // swizzle term

  // staging addressing (pre-swizzled global source, linear LDS dest)
  const int srow = tid >> 3;                              // 0..63 (+64/chunk)
  const int skb  = ((tid & 7) << 4) ^ ((srow & 7) << 4);  // byte col in [0,128)
  const unsigned short* ga = A  + (size_t)(bm + srow) * NN + (skb >> 1);
  const unsigned short* gb = Bt + (size_t)(bn + srow) * NN + (skb >> 1);

  f32x4 z = {0.f, 0.f, 0.f, 0.f};
  f32x4 acc[4][4];
  #pragma unroll
  for (int i = 0; i < 4; ++i)
    #pragma unroll
    for (int j = 0; j < 4; ++j) acc[i][j] = z;

#define STAGE_A3(NXT, KO)                                                      \
  gload_lds16(ga + (size_t)0 * 64 * NN + (KO), As + (NXT)*16384 + wv*512 + 0*4096); \
  gload_lds16(ga + (size_t)1 * 64 * NN + (KO), As + (NXT)*16384 + wv*512 + 1*4096); \
  gload_lds16(ga + (size_t)2 * 64 * NN + (KO), As + (NXT)*16384 + wv*512 + 2*4096);

#define STAGE_B3(NXT, KO)                                                      \
  gload_lds16(ga + (size_t)3 * 64 * NN + (KO), As + (NXT)*16384 + wv*512 + 3*4096); \
  gload_lds16(gb + (size_t)0 * 64 * NN + (KO), Bs + (NXT)*8192  + wv*512 + 0*4096); \
  gload_lds16(gb + (size_t)1 * 64 * NN + (KO), Bs + (NXT)*8192  + wv*512 + 1*4096);

#define PHASE(CUR, KS) {                                                       \
    const unsigned short* Ab = As + (CUR) * 16384;                             \
    const unsigned short* Bb = Bs + (CUR) * 8192;                              \
    const int ko = ((((KS) << 6) + (fq << 4)) ^ xorv) >> 1;                    \
    short8 av[4], bv[4];                                                       \
    _Pragma("unroll")                                                          \
    for (int mi = 0; mi < 4; ++mi)                                             \
      av[mi] = *(const short8*)(Ab + (wr * 64 + mi * 16 + fr) * 64 + ko);      \
    _Pragma("unroll")                                                          \
    for (int ni = 0; ni < 4; ++ni)                                             \
      bv[ni] = *(const short8*)(Bb + (wc * 64 + ni * 16 + fr) * 64 + ko);      \
    __builtin_amdgcn_s_setprio(1);                                             \
    _Pragma("unroll")                                                          \
    for (int mi = 0; mi < 4; ++mi)                                             \
      _Pragma("unroll")                                                        \
      for (int ni = 0; ni < 4; ++ni)                                           \
        acc[mi][ni] = __builtin_amdgcn_mfma_f32_16x16x32_bf16(av[mi], bv[ni], acc[mi][ni], 0, 0, 0); \
    __builtin_amdgcn_s_setprio(0);                                             \
  }

  // TILE: stage issues for tile t+2 interleaved into the two compute phases.
  // Safe: stages write buf[(t+2)%3] == buf[(t-1)%3], fully consumed before
  // the barrier at end of tile t-1. One barrier per tile.
#define TILE(CUR, NXT, WAITSTR) {                                              \
    STAGE_A3(NXT, kq)                                                          \
    PHASE(CUR, 0)                                                              \
    STAGE_B3(NXT, kq)                                                          \
    PHASE(CUR, 1)                                                              \
    asm volatile("s_waitcnt " WAITSTR ::: "memory");                           \
    __builtin_amdgcn_s_barrier();                                              \
    kq += 64;                                                                  \
  }
#define TILE_NOSTAGE(CUR, WAITSTR) {                                           \
    PHASE(CUR, 0)                                                              \
    PHASE(CUR, 1)                                                              \
    asm volatile("s_waitcnt " WAITSTR ::: "memory");                           \
    __builtin_amdgcn_s_barrier();                                              \
  }

  // ---- prologue: stage tile0 -> buf0, tile1 -> buf1 ----
  STAGE_A3(0, 0) STAGE_B3(0, 0)
  STAGE_A3(1, 64) STAGE_B3(1, 64)
  asm volatile("s_waitcnt vmcnt(6)" ::: "memory");   // tile0 landed
  __builtin_amdgcn_s_barrier();

  int kq = 128;   // global k-element col of tile t+2 (t=0 -> 128)

  // ---- main loop: tiles 0..59 (20 groups of 3), then 60..63 ----
  #pragma unroll 1
  for (int g = 0; g < 20; ++g) {
    TILE(0, 2, "vmcnt(6)")
    TILE(1, 0, "vmcnt(6)")
    TILE(2, 1, "vmcnt(6)")
  }
  TILE(0, 2, "vmcnt(6)")        // t=60, stages 62
  TILE(1, 0, "vmcnt(6)")        // t=61, stages 63
  TILE_NOSTAGE(2, "vmcnt(0)")   // t=62, drain: tile 63 ready
  PHASE(0, 0)                    // t=63
  PHASE(0, 1)

#undef TILE
#undef TILE_NOSTAGE
#undef PHASE
#undef STAGE_A3
#undef STAGE_B3

  // ---- epilogue: bias + relu, store bf16 ----
  const int cr = (lane >> 4) * 4;
  const int cc = lane & 15;
  #pragma unroll
  for (int ni = 0; ni < 4; ++ni) {
    int col = bn + wc * 64 + ni * 16 + cc;     // j
    float bias = b1[(ni * 16 + cc) & 63];
    #pragma unroll
    for (int mi = 0; mi < 4; ++mi) {
      #pragma unroll
      for (int r = 0; r < 4; ++r) {
        int row = bm + wr * 64 + mi * 16 + cr + r;   // n
        float v = acc[mi][ni][r] + bias;
        v = v > 0.f ? v : 0.f;
        H[(long)row * NJ + col] = f2bf(v);
      }
    }
  }
}

// ---------- K3: partial[b][c][h] = sum_{n in chunk c} adj[q_b][n] * H[n][b*64+h] ----------
__global__ __launch_bounds__(256) void k_agg(const float* __restrict__ adj,
                                             const int* __restrict__ q_ids,
                                             const unsigned short* __restrict__ H,
                                             float* __restrict__ partial) {
  int b = blockIdx.x;        // 0..31
  int c = blockIdx.y;        // 0..15
  int h = threadIdx.x & 63;
  int w = threadIdx.x >> 6;
  int q = q_ids[b];
  const float* arow = adj + (long)q * NN;
  int j = b * FHID + h;
  float s = 0.f;
  int n0 = c * 256;
  for (int n = n0 + w; n < n0 + 256; n += 4)
    s += arow[n] * bf2f(H[(long)n * NJ + j]);
  __shared__ float red[4][64];
  red[w][h] = s;
  __syncthreads();
  if (w == 0)
    partial[((b << 4) + c) * 64 + h] = red[0][h] + red[1][h] + red[2][h] + red[3][h];
}

// ---------- K4: out[b][l] = sum_h agg[b][h]*W2[h][l] + b2[l] ----------
__global__ __launch_bounds__(1024) void k_out(const float* __restrict__ partial,
                                              const float* __restrict__ W2,
                                              const float* __restrict__ b2,
                                              float* __restrict__ out) {
  __shared__ float aggs[BATCH * FHID];   // 2048
  int t = threadIdx.x;
  for (int idx = t; idx < BATCH * FHID; idx += 1024) {
    int base = (idx >> 6) * (16 * 64) + (idx & 63);
    float s = 0.f;
    #pragma unroll
    for (int c = 0; c < 16; ++c) s += partial[base + c * 64];
    aggs[idx] = s;
  }
  __syncthreads();
  int b = t >> 5, l = t & 31;
  float o = b2[l];
  #pragma unroll
  for (int h = 0; h < FHID; ++h) o += aggs[b * FHID + h] * W2[h * 32 + l];
  out[b * 32 + l] = o;
}

extern "C" void kernel_launch(void* const* d_in, const int* in_sizes, int n_in,
                              void* d_out, int out_size, void* d_ws, size_t ws_size,
                              hipStream_t stream) {
  const float* x   = (const float*)d_in[0];
  const int*   q   = (const int*)d_in[1];
  const float* adj = (const float*)d_in[2];
  const float* W1  = (const float*)d_in[3];
  const float* b1  = (const float*)d_in[4];
  const float* W2  = (const float*)d_in[5];
  const float* b2  = (const float*)d_in[6];
  float* out = (float*)d_out;

  char* ws = (char*)d_ws;
  unsigned short* adjb   = (unsigned short*)ws;                              // 32 MB
  unsigned short* St     = (unsigned short*)(ws + (size_t)32 * 1024 * 1024); // 16 MB
  unsigned short* H      = (unsigned short*)(ws + (size_t)48 * 1024 * 1024); // 16 MB
  float*          partial= (float*)(ws + (size_t)64 * 1024 * 1024);          // 128 KB

  // K0: adj -> bf16  (16.78M elems / 4 per thread)
  k_convert<<<(NN * NN / 4) / 256, 256, 0, stream>>>(adj, adjb);
  // K1: support^T
  k_support<<<(BATCH * NN) / 256, 256, 0, stream>>>(x, W1, St);
  // K2: big GEMM + bias + relu  (256x128 tiles)
  dim3 g2(NN / 256, NJ / 128);
  k_gemm<<<g2, 512, 0, stream>>>(adjb, St, b1, H);
  // K3: row-gather aggregation
  dim3 g3(BATCH, 16);
  k_agg<<<g3, 256, 0, stream>>>(adj, q, H, partial);
  // K4: final tiny GEMM
  k_out<<<1, 1024, 0, stream>>>(partial, W2, b2, out);
}